// Round 4
// baseline (48.163 us; speedup 1.0000x reference)
//
#include <hip/hip_runtime.h>

// 2x upsample with binomial blur [1,4,6,4,1]/8 per axis, edge clamp.
// Per-axis closed form (clamp c() to [0,47]):
//   y[2a]   = (x[c(a-1)] + 6*x[a] + x[c(a+1)]) / 8
//   y[2a+1] = (x[a] + x[c(a+1)]) / 2
// Each thread: 2x2x2-input block -> 4x4x4 output block (64 floats).
// Streaming-d restructure: per d-neighbor row-quad, compute W+H combines into
// rolling He/Ho[i]; emit output plane-pair ap as soon as He/Ho[ap..ap+2] are
// ready (i>=2). Cuts peak live registers (~64 fewer than holding r[4][4][4])
// and issues stores interleaved with the last loads.
// All /8,/2 scaling deferred to one exact power-of-two multiply per output.

typedef float f32x4 __attribute__((ext_vector_type(4)));

constexpr int DIN = 48, HIN = 48, WIN = 48;
constexpr int HW = HIN * WIN;          // 2304
constexpr int HOUT = 96, WOUT = 96;
constexpr int PS = HOUT * WOUT;        // output d-plane stride, 9216
constexpr int NC = 64;
constexpr int THREADS = NC * 24 * 24 * 24;  // 884736

__global__ __launch_bounds__(256, 4) void Upsample2x2x2_kernel(
    const float* __restrict__ x, float* __restrict__ out)
{
    int idx = blockIdx.x * 256 + threadIdx.x;
    int t   = idx % 24;        // input w0 = 2t, outputs w 4t..4t+3
    int tmp = idx / 24;
    int b0h = tmp % 24;
    tmp    /= 24;
    int a0h = tmp % 24;
    int nc  = tmp / 24;

    const int a0 = a0h * 2, b0 = b0h * 2, w0 = t * 2;
    const float* __restrict__ xb = x + nc * (DIN * HW);

    const int ai[4] = { a0 > 0 ? a0 - 1 : 0, a0, a0 + 1,
                        a0 + 2 < DIN ? a0 + 2 : DIN - 1 };
    const int bi[4] = { b0 > 0 ? b0 - 1 : 0, b0, b0 + 1,
                        b0 + 2 < HIN ? b0 + 2 : HIN - 1 };
    const int wm = w0 > 0 ? w0 - 1 : 0;
    const int wp = w0 + 2 < WIN ? w0 + 2 : WIN - 1;

    float* __restrict__ ob = out + nc * (2 * DIN * PS);
    const int obase = (a0 * 2 * HOUT + b0 * 2) * WOUT + t * 4;

    // rolling H-combined state per d-neighbor i, per h-output-pair win
    float He[4][2][4], Ho[4][2][4];

    #pragma unroll
    for (int i = 0; i < 4; i++) {
        const float* __restrict__ xd = xb + ai[i] * HW;

        // W-stage for the 4 h-neighbor rows of this d
        float rr[4][4];
        #pragma unroll
        for (int j = 0; j < 4; j++) {
            const float* __restrict__ row = xd + bi[j] * WIN;
            float2 m = *reinterpret_cast<const float2*>(row + w0);  // 8B aligned
            float u0 = row[wm];
            float u3 = row[wp];
            float u1 = m.x, u2 = m.y;
            rr[j][0] = fmaf(6.f, u1, u0) + u2;
            rr[j][1] = u1 + u2;
            rr[j][2] = fmaf(6.f, u2, u1) + u3;
            rr[j][3] = u2 + u3;
        }

        // H-stage
        #pragma unroll
        for (int win = 0; win < 2; win++)
            #pragma unroll
            for (int k = 0; k < 4; k++) {
                He[i][win][k] = fmaf(6.f, rr[win + 1][k], rr[win][k]) + rr[win + 2][k];
                Ho[i][win][k] = rr[win + 1][k] + rr[win + 2][k];
            }

        // D-stage + store as soon as a window of 3 is complete
        if (i >= 2) {
            const int ap = i - 2;   // output d-pair 2(a0+ap), +1
            #pragma unroll
            for (int win = 0; win < 2; win++) {
                float vee[4], voe[4], veo[4], voo[4];
                #pragma unroll
                for (int k = 0; k < 4; k++) {
                    vee[k] = fmaf(6.f, He[ap + 1][win][k], He[ap][win][k]) + He[ap + 2][win][k];
                    voe[k] = He[ap + 1][win][k] + He[ap + 2][win][k];
                    veo[k] = fmaf(6.f, Ho[ap + 1][win][k], Ho[ap][win][k]) + Ho[ap + 2][win][k];
                    voo[k] = Ho[ap + 1][win][k] + Ho[ap + 2][win][k];
                }
                const int rbase = obase + ap * 2 * PS + win * 2 * WOUT;
                // scales: per-axis even=1/8, odd=1/2; w-parity alternates in lane
                f32x4 s0 = { vee[0] * (1.f/512), vee[1] * (1.f/128),
                             vee[2] * (1.f/512), vee[3] * (1.f/128) };
                f32x4 s1 = { veo[0] * (1.f/128), veo[1] * (1.f/32),
                             veo[2] * (1.f/128), veo[3] * (1.f/32) };
                f32x4 s2 = { voe[0] * (1.f/128), voe[1] * (1.f/32),
                             voe[2] * (1.f/128), voe[3] * (1.f/32) };
                f32x4 s3 = { voo[0] * (1.f/32),  voo[1] * (1.f/8),
                             voo[2] * (1.f/32),  voo[3] * (1.f/8) };
                __builtin_nontemporal_store(s0, reinterpret_cast<f32x4*>(ob + rbase));
                __builtin_nontemporal_store(s1, reinterpret_cast<f32x4*>(ob + rbase + WOUT));
                __builtin_nontemporal_store(s2, reinterpret_cast<f32x4*>(ob + rbase + PS));
                __builtin_nontemporal_store(s3, reinterpret_cast<f32x4*>(ob + rbase + PS + WOUT));
            }
        }
    }
}

extern "C" void kernel_launch(void* const* d_in, const int* in_sizes, int n_in,
                              void* d_out, int out_size, void* d_ws, size_t ws_size,
                              hipStream_t stream) {
    const float* x = (const float*)d_in[0];
    float* out = (float*)d_out;
    int blocks = THREADS / 256;  // 3456, exact
    Upsample2x2x2_kernel<<<blocks, 256, 0, stream>>>(x, out);
}